// Round 1
// 241.061 us; speedup vs baseline: 1.0194x; 1.0194x over previous
//
#include <hip/hip_runtime.h>

// MultiQueryAttention with kv_len == 1: softmax over a singleton axis is
// identically 1, so the output is independent of query/Wq/key/Wk.
//   V[b,d]      = value[b,:]·Wv[:,d] + bv[d]                      (8 x 64)
//   out_vec[b,j]= sum_c V[b, c&63] * Wo[c,j] + bo[j]              (8 x 1024)
//   out[b,s,:]  = out_vec[b,:]  for all s                         (8 x 4096 x 1024)
//
// Single fused kernel, fully self-sufficient blocks (no inter-kernel or
// inter-block dependency): grid = 8 b x 16 j-slices x 4 row-groups = 512
// blocks (2/CU). Each block redundantly recomputes V[b] (Wv is 256 KB,
// L2-hot) and its 64-column out_vec slice (256 KB of Wo, float4-vectorized),
// then nontemporal-streams the 256 B slice across its 1024 rows.
// Redundancy cost: ~256 MB of L2 reads (~7 us aggregate, overlapped across
// blocks) vs. the old 2-kernel version's launch gap + full serialization of
// the broadcast behind k_outvec.

#define D_MODEL 1024
#define HEAD_DIM 64
#define B_SIZE 8
#define S_LEN 4096
#define ROWGROUPS 4  // blocks per (b,jc); each covers S_LEN/ROWGROUPS rows

typedef float vfloat4 __attribute__((ext_vector_type(4)));

__global__ __launch_bounds__(256) void k_fused(
    const float* __restrict__ value, const float4* __restrict__ Wv4,
    const float4* __restrict__ bv4, const float4* __restrict__ Wo4,
    const float4* __restrict__ bo4, vfloat4* __restrict__ out4) {
  int blk = blockIdx.x;
  int b = blk >> 6;         // 0..7   (64 blocks per b)
  int jc = (blk >> 2) & 15; // 0..15  (64-column slice)
  int rg = blk & 3;         // 0..3   (1024-row group)
  int t = threadIdx.x;

  // --- phase 1: V[b,:] = value[b,:]·Wv + bv ---
  __shared__ __align__(16) float Vsh[64];
  {
    int d4 = t & 15;  // float4 column (64 floats = 16 float4)
    int kp = t >> 4;  // 0..15, 64 k each
    const float* vrow = value + b * D_MODEL;
    float4 acc = make_float4(0.f, 0.f, 0.f, 0.f);
    int k0 = kp * 64;
#pragma unroll 8
    for (int i = 0; i < 64; ++i) {
      int k = k0 + i;
      float v = vrow[k];            // 16 lanes share address -> L1 broadcast
      float4 w = Wv4[k * 16 + d4];  // 16 consecutive float4 = 256B segment
      acc.x += v * w.x;
      acc.y += v * w.y;
      acc.z += v * w.z;
      acc.w += v * w.w;
    }
    __shared__ float4 red[16][16];
    red[kp][d4] = acc;
    __syncthreads();
    if (t < 16) {
      float4 s = bv4[t];
#pragma unroll
      for (int p = 0; p < 16; ++p) {
        float4 r = red[p][t];
        s.x += r.x;
        s.y += r.y;
        s.z += r.z;
        s.w += r.w;
      }
      ((float4*)Vsh)[t] = s;
    }
    __syncthreads();
  }

  // --- phase 2: out_vec slice, j in [jc*64, jc*64+64), float4 reads ---
  // 16 lanes x float4 cover the 64 columns; 16 parts x 64 c each.
  int j4 = t & 15;
  int part = t >> 4;  // 0..15
  int jb4 = jc * 16;  // float4 column base
  __shared__ __align__(16) float slice[64];
  {
    float4 acc = make_float4(0.f, 0.f, 0.f, 0.f);
    int c0 = part * 64;
#pragma unroll 8
    for (int i = 0; i < 64; ++i) {
      int c = c0 + i;
      float v = Vsh[c & 63];               // wave-uniform -> LDS broadcast
      float4 w = Wo4[c * 256 + jb4 + j4];  // 16 lanes = 256B segment
      acc.x += v * w.x;
      acc.y += v * w.y;
      acc.z += v * w.z;
      acc.w += v * w.w;
    }
    __shared__ float4 red2[16][16];
    red2[part][j4] = acc;
    __syncthreads();
    if (t < 16) {
      float4 s = bo4[jb4 + t];
#pragma unroll
      for (int p = 0; p < 16; ++p) {
        float4 r = red2[p][t];
        s.x += r.x;
        s.y += r.y;
        s.z += r.z;
        s.w += r.w;
      }
      ((float4*)slice)[t] = s;
    }
    __syncthreads();
  }

  // --- phase 3: broadcast rows [rg*1024, +1024), cols [jc*64, +64) ---
  // Wave writes 4 rows x 256 B contiguous (full 128B lines), nontemporal.
  vfloat4 v = ((const vfloat4*)slice)[j4];
  int r0 = rg * (S_LEN / ROWGROUPS) + part;
  vfloat4* p = out4 + (size_t)b * (S_LEN * 256) + (size_t)r0 * 256 + jb4 + j4;
#pragma unroll 8
  for (int i = 0; i < 64; ++i) {
    __builtin_nontemporal_store(v, p);
    p += 16 * 256;  // 16 rows ahead
  }
}

extern "C" void kernel_launch(void* const* d_in, const int* in_sizes, int n_in,
                              void* d_out, int out_size, void* d_ws,
                              size_t ws_size, hipStream_t stream) {
  // setup_inputs order: query(0) key(1) value(2) Wq(3) bq(4) Wk(5) bk(6)
  //                     Wv(7) bv(8) Wo(9) bo(10)
  const float* value = (const float*)d_in[2];
  const float* Wv = (const float*)d_in[7];
  const float* bv = (const float*)d_in[8];
  const float* Wo = (const float*)d_in[9];
  const float* bo = (const float*)d_in[10];

  k_fused<<<B_SIZE * 16 * ROWGROUPS, 256, 0, stream>>>(
      value, (const float4*)Wv, (const float4*)bv, (const float4*)Wo,
      (const float4*)bo, (vfloat4*)d_out);
}

// Round 2
// 240.604 us; speedup vs baseline: 1.0214x; 1.0019x over previous
//
#include <hip/hip_runtime.h>

// MultiQueryAttention with kv_len == 1: softmax over a singleton axis is
// identically 1, so the output is independent of query/Wq/key/Wk.
//   V[b,d]      = value[b,:]·Wv[:,d] + bv[d]                      (8 x 64)
//   out_vec[b,j]= sum_c V[b, c&63] * Wo[c,j] + bo[j]              (8 x 1024)
//   out[b,s,:]  = out_vec[b,:]  for all s                         (8 x 4096 x 1024)
//
// Single fused kernel, fully self-sufficient blocks (no inter-kernel or
// inter-block dependency): grid = 8 b x 16 j-slices x 2 row-groups = 256
// blocks (1/CU — every CU issues stores; fills prove write BW saturates at
// ~10% occupancy). Each block redundantly recomputes V[b] (Wv, 256 KB,
// L2-hot) and its 64-column out_vec slice (256 KB of Wo), then
// nontemporal-streams the 256 B slice across its 2048 rows.
//
// ROWGROUPS 4->2 rationale: the preamble is L2-BW-bound (512 blocks x 512 KB
// = 256 MB concurrent L2 reads ~= 7.4 us at 34.5 TB/s, serialized before the
// ~19.7 us store phase). Halving block count halves that traffic (~3.7 us)
// while keeping all 256 CUs storing.

#define D_MODEL 1024
#define HEAD_DIM 64
#define B_SIZE 8
#define S_LEN 4096
#define ROWGROUPS 2  // blocks per (b,jc); each covers S_LEN/ROWGROUPS rows

typedef float vfloat4 __attribute__((ext_vector_type(4)));

__global__ __launch_bounds__(256) void k_fused(
    const float* __restrict__ value, const float4* __restrict__ Wv4,
    const float4* __restrict__ bv4, const float4* __restrict__ Wo4,
    const float4* __restrict__ bo4, vfloat4* __restrict__ out4) {
  int blk = blockIdx.x;
  int b = blk >> 5;          // 0..7   (32 blocks per b)
  int jc = (blk >> 1) & 15;  // 0..15  (64-column slice)
  int rg = blk & 1;          // 0..1   (2048-row group)
  int t = threadIdx.x;

  // --- phase 1: V[b,:] = value[b,:]·Wv + bv ---
  __shared__ __align__(16) float Vsh[64];
  {
    int d4 = t & 15;  // float4 column (64 floats = 16 float4)
    int kp = t >> 4;  // 0..15, 64 k each
    const float* vrow = value + b * D_MODEL;
    float4 acc = make_float4(0.f, 0.f, 0.f, 0.f);
    int k0 = kp * 64;
#pragma unroll 8
    for (int i = 0; i < 64; ++i) {
      int k = k0 + i;
      float v = vrow[k];            // 16 lanes share address -> L1 broadcast
      float4 w = Wv4[k * 16 + d4];  // 16 consecutive float4 = 256B segment
      acc.x += v * w.x;
      acc.y += v * w.y;
      acc.z += v * w.z;
      acc.w += v * w.w;
    }
    __shared__ float4 red[16][16];
    red[kp][d4] = acc;
    __syncthreads();
    if (t < 16) {
      float4 s = bv4[t];
#pragma unroll
      for (int p = 0; p < 16; ++p) {
        float4 r = red[p][t];
        s.x += r.x;
        s.y += r.y;
        s.z += r.z;
        s.w += r.w;
      }
      ((float4*)Vsh)[t] = s;
    }
    __syncthreads();
  }

  // --- phase 2: out_vec slice, j in [jc*64, jc*64+64), float4 reads ---
  // 16 lanes x float4 cover the 64 columns; 16 parts x 64 c each.
  int j4 = t & 15;
  int part = t >> 4;  // 0..15
  int jb4 = jc * 16;  // float4 column base
  __shared__ __align__(16) float slice[64];
  {
    float4 acc = make_float4(0.f, 0.f, 0.f, 0.f);
    int c0 = part * 64;
#pragma unroll 8
    for (int i = 0; i < 64; ++i) {
      int c = c0 + i;
      float v = Vsh[c & 63];               // wave-uniform -> LDS broadcast
      float4 w = Wo4[c * 256 + jb4 + j4];  // 16 lanes = 256B segment
      acc.x += v * w.x;
      acc.y += v * w.y;
      acc.z += v * w.z;
      acc.w += v * w.w;
    }
    __shared__ float4 red2[16][16];
    red2[part][j4] = acc;
    __syncthreads();
    if (t < 16) {
      float4 s = bo4[jb4 + t];
#pragma unroll
      for (int p = 0; p < 16; ++p) {
        float4 r = red2[p][t];
        s.x += r.x;
        s.y += r.y;
        s.z += r.z;
        s.w += r.w;
      }
      ((float4*)slice)[t] = s;
    }
    __syncthreads();
  }

  // --- phase 3: broadcast rows [rg*2048, +2048), cols [jc*64, +64) ---
  // Wave writes 4 rows x 256 B contiguous (full 128B lines), nontemporal.
  vfloat4 v = ((const vfloat4*)slice)[j4];
  int r0 = rg * (S_LEN / ROWGROUPS) + part;
  vfloat4* p = out4 + (size_t)b * (S_LEN * 256) + (size_t)r0 * 256 + jb4 + j4;
#pragma unroll 8
  for (int i = 0; i < 128; ++i) {
    __builtin_nontemporal_store(v, p);
    p += 16 * 256;  // 16 rows ahead
  }
}

extern "C" void kernel_launch(void* const* d_in, const int* in_sizes, int n_in,
                              void* d_out, int out_size, void* d_ws,
                              size_t ws_size, hipStream_t stream) {
  // setup_inputs order: query(0) key(1) value(2) Wq(3) bq(4) Wk(5) bk(6)
  //                     Wv(7) bv(8) Wo(9) bo(10)
  const float* value = (const float*)d_in[2];
  const float* Wv = (const float*)d_in[7];
  const float* bv = (const float*)d_in[8];
  const float* Wo = (const float*)d_in[9];
  const float* bo = (const float*)d_in[10];

  k_fused<<<B_SIZE * 16 * ROWGROUPS, 256, 0, stream>>>(
      value, (const float4*)Wv, (const float4*)bv, (const float4*)Wo,
      (const float4*)bo, (vfloat4*)d_out);
}